// Round 14
// baseline (572.848 us; speedup 1.0000x reference)
//
#include <hip/hip_runtime.h>
#include <hip/hip_bf16.h>
#include <cstdio>

#define NN 50000
#define NE 800000
#define CC 128
#define EDIM 64
#define HIDN 512

using bf16 = __hip_bfloat16;
typedef short sh8 __attribute__((ext_vector_type(8)));
typedef float f32x4 __attribute__((ext_vector_type(4)));

static __device__ __forceinline__ float b2f(bf16 v){ return __bfloat162float(v); }
static __device__ __forceinline__ bf16 f2b(float v){ return __float2bfloat16(v); }
static __device__ __forceinline__ float u2f(unsigned short u){
    union { unsigned int i; float f; } w; w.i = ((unsigned int)u) << 16; return w.f;
}
static __device__ __forceinline__ unsigned short f2u(float f){
    bf16 b = __float2bfloat16(f);
    return *reinterpret_cast<unsigned short*>(&b);
}
static __device__ __forceinline__ float2 loadbf2(const bf16* p){
    __hip_bfloat162 v = *reinterpret_cast<const __hip_bfloat162*>(p);
    return make_float2(__bfloat162float(v.x), __bfloat162float(v.y));
}
static __device__ __forceinline__ float gelu_tanh(float x){
    const float c = 0.7978845608028654f; // sqrt(2/pi)
    float u = c * (x + 0.044715f * x * x * x);
    return x / (1.0f + __expf(-2.0f * u));   // x*sigmoid(2u) == 0.5x(1+tanh(u))
}

// ---------------- workspace layout ----------------
constexpr size_t AL(size_t x){ return (x + 255) & ~(size_t)255; }
constexpr size_t OFF_FLAG = 0;                                   // int[16]
constexpr size_t OFF_DEG  = 256;
constexpr size_t OFF_ROW  = AL(OFF_DEG + (size_t)(NN + 1) * 4);
constexpr size_t OFF_CUR  = AL(OFF_ROW + (size_t)(NN + 1) * 4); // NN+1 ints
constexpr size_t OFF_SRC  = AL(OFF_CUR + (size_t)(NN + 1) * 4);
constexpr size_t OFF_DST  = AL(OFF_SRC + (size_t)NE * 4);
constexpr size_t OFF_QC   = AL(OFF_DST + (size_t)NE * 4);
constexpr size_t OFF_KC   = AL(OFF_QC  + (size_t)NN * CC * 2);
constexpr size_t OFF_VC   = AL(OFF_KC  + (size_t)NN * CC * 2);
constexpr size_t OFF_ATT  = AL(OFF_VC  + (size_t)NN * CC * 2);
constexpr size_t OFF_PRM  = AL(OFF_ATT + (size_t)NN * CC * 2);   // biases/LN only
constexpr size_t PRM_ELEMS = 4096;
constexpr size_t OFF_ALP  = AL(OFF_PRM + PRM_ELEMS * 2);         // alpha: E*8 bf16
constexpr size_t OFF_EAP  = AL(OFF_ALP + (size_t)NE * 8 * 2);    // ea CSR-perm: E*64 bf16
constexpr size_t OFF_SP   = AL(OFF_EAP + (size_t)NE * EDIM * 2); // src CSR-perm: E ints
constexpr size_t OFF_XRC  = AL(OFF_SP  + (size_t)NE * 4);
constexpr size_t OFF_WFQ  = AL(OFF_XRC + (size_t)NN * CC * 2);
constexpr size_t OFF_WFK  = OFF_WFQ + 32768;
constexpr size_t OFF_WFV  = OFF_WFK + 32768;
constexpr size_t OFF_WFS  = OFF_WFV + 32768;
constexpr size_t OFF_WFP  = OFF_WFS + 32768;
constexpr size_t OFF_WF1  = OFF_WFP + 32768;
constexpr size_t OFF_WF2  = OFF_WF1 + 131072;
constexpr size_t OFF_WFE  = OFF_WF2 + 131072;    // we fragment-linear, 16 KB
constexpr size_t OFF_BSUM = OFF_WFE + 16384;     // 64 ints
constexpr size_t WS_NEED  = OFF_BSUM + 256;

// ---------------- dtype detection ----------------
__global__ void k_detect(const unsigned short* xw, const unsigned int* ew, int* flags){
    __shared__ int sw, sz;
    if (threadIdx.x == 0){ sw = 0; sz = 0; }
    __syncthreads();
    int w = 0;
    for (int i = threadIdx.x; i < 8192; i += 256){
        unsigned e = (xw[i] >> 7) & 0xFF;
        if (e == 0xFF || (e != 0 && (e < 0x60 || e > 0x90))) w++;
    }
    atomicAdd(&sw, w);
    int z = 0;
    for (int i = threadIdx.x; i < 2048; i += 256)
        if (ew[2*i+1] == 0u) z++;
    atomicAdd(&sz, z);
    __syncthreads();
    if (threadIdx.x == 0){
        flags[0] = (sw > 2048) ? 1 : 0;   // 1: floats are f32 on device
        flags[1] = (sz > 1536) ? 1 : 0;   // 1: edge_index is int64 on device
    }
}

// ---------------- canonicalizers (biases / LN params only) ----------------
struct CvtJob { const void* s; bf16* d; int n; };
struct CvtJobs { CvtJob j[12]; };
__global__ void k_cvt_all(CvtJobs jobs, const int* flags){
    const int f = flags[0];
    const int e = blockIdx.x >> 1;           // 2 blocks per entry
    const CvtJob J = jobs.j[e];
    const int stride = 2 * 256;
    for (int i = (blockIdx.x & 1) * 256 + threadIdx.x; i < J.n; i += stride){
        if (f) J.d[i] = f2b(((const float*)J.s)[i]);
        else   J.d[i] = ((const bf16*)J.s)[i];
    }
}

// indices + degree histogram in one pass
__global__ void k_cvt_idx(const int* e32, int* srcI, int* dstI, int* deg, const int* flags){
    const int f = flags[1];
    int i = blockIdx.x * blockDim.x + threadIdx.x;
    const int stride = gridDim.x * blockDim.x;
    if (f){
        const long long* e64 = (const long long*)e32;
        for (; i < NE; i += stride){
            srcI[i] = (int)e64[i];
            const int d = (int)e64[NE + i];
            dstI[i] = d;
            atomicAdd(&deg[d], 1);
        }
    } else {
        for (; i < NE; i += stride){
            srcI[i] = e32[i];
            const int d = e32[NE + i];
            dstI[i] = d;
            atomicAdd(&deg[d], 1);
        }
    }
}

// ---------------- weight fragment-linear pre-transform (reads RAW inputs) ----------
// WF[((ct*KS+ks)*64+lane)*8+j] = W[ks*32+(lane>>4)*8+j][ct*16+(lane&15)]
struct WJob { const void* W; bf16* WF; int K; int N; };
struct WJobs { WJob j[8]; };
__global__ void k_wprep_all(WJobs jobs, const int* flags){
    const int f = flags[0];
    const WJob J = jobs.j[blockIdx.x / 48];
    const int KS = J.K >> 5;
    const int total = J.K * J.N;
    for (int o = (blockIdx.x % 48) * 256 + threadIdx.x; o < total; o += 48 * 256){
        const int j  = o & 7;
        const int ln = (o >> 3) & 63;
        const int tt = o >> 9;
        const int ks = tt % KS, ct = tt / KS;
        const int kk = (ks << 5) + ((ln >> 4) << 3) + j;
        const int c  = (ct << 4) + (ln & 15);
        const int src = kk * J.N + c;
        J.WF[o] = f ? f2b(((const float*)J.W)[src]) : ((const bf16*)J.W)[src];
    }
}

// swizzled LDS addressing, 16B chunks XORed with low row bits
#define ASWZ(row, chunk)  (((row) << 8)  + ((((chunk) ^ ((row) & 15))) << 4))   // 256B rows
#define HSWZ(row, chunk)  (((row) << 10) + ((((chunk) ^ ((row) & 15))) << 4))   // 1024B rows
#define EASWZ(row, chunk) (((row) << 7)  + ((((chunk) ^ ((row) & 7)))  << 4))   // 128B rows

// one [16 x 128] row-tile times fragment-linear W[128x128], bias add, bf16 store
static __device__ __forceinline__ void gemm_nodes_128(
    const unsigned short* Abase, int row0, int lane,
    const bf16* __restrict__ WF, const bf16* __restrict__ bias,
    bf16* __restrict__ outp, int n0)
{
    const int rA = row0 + (lane & 15);
    sh8 af[4];
    #pragma unroll
    for (int ks = 0; ks < 4; ++ks)
        af[ks] = *(const sh8*)((const char*)Abase + ASWZ(rA, (ks << 2) + (lane >> 4)));
    f32x4 acc[8] = {};
    #pragma unroll
    for (int ks = 0; ks < 4; ++ks)
        #pragma unroll
        for (int ct = 0; ct < 8; ++ct){
            sh8 bfr = *(const sh8*)(WF + ((size_t)((ct << 2) + ks) * 64 + lane) * 8);
            acc[ct] = __builtin_amdgcn_mfma_f32_16x16x32_bf16(af[ks], bfr, acc[ct], 0, 0, 0);
        }
    #pragma unroll
    for (int ct = 0; ct < 8; ++ct){
        const int c = (ct << 4) + (lane & 15);
        const float bv = b2f(bias[c]);
        #pragma unroll
        for (int i = 0; i < 4; ++i){
            const int r = row0 + ((lane >> 4) << 2) + i;
            if (n0 + r < NN)
                outp[(size_t)(n0 + r) * CC + c] = f2b(acc[ct][i] + bv);
        }
    }
}

// ---------------- kernel A: LN1 + q/k/v/xr MFMA GEMMs (64 nodes/block) ----------------
__global__ __launch_bounds__(256) void k_node_pre2(
    const void* __restrict__ x_raw, const int* __restrict__ flags,
    const bf16* __restrict__ WFq, const bf16* __restrict__ bq,
    const bf16* __restrict__ WFk, const bf16* __restrict__ bk,
    const bf16* __restrict__ WFv, const bf16* __restrict__ bv,
    const bf16* __restrict__ WFs, const bf16* __restrict__ bs,
    const bf16* __restrict__ g,  const bf16* __restrict__ bb,
    bf16* __restrict__ q, bf16* __restrict__ k, bf16* __restrict__ v,
    bf16* __restrict__ xr)
{
    __shared__ unsigned short A[64 * 128];      // 16 KB, swizzled
    const int t = threadIdx.x, lane = t & 63, wid = t >> 6;
    const int n0 = blockIdx.x * 64;
    const int row0 = wid * 16;

    if (flags[0]){
        const float* x = (const float*)x_raw;
        #pragma unroll
        for (int it = 0; it < 8; ++it){
            const int idx = lane + 64 * it;      // 512 units of 4 f32, own 16 rows
            const int row = row0 + (idx >> 5), c = (idx & 31) << 2;
            float4 a = make_float4(0.f, 0.f, 0.f, 0.f);
            if (n0 + row < NN)
                a = *(const float4*)&x[(size_t)(n0 + row) * CC + c];
            ushort4 b;
            b.x = f2u(a.x); b.y = f2u(a.y); b.z = f2u(a.z); b.w = f2u(a.w);
            *(ushort4*)((char*)A + ASWZ(row, c >> 3) + ((c & 7) << 1)) = b;
        }
    } else {
        const bf16* x = (const bf16*)x_raw;
        #pragma unroll
        for (int it = 0; it < 4; ++it){
            const int idx = lane + 64 * it;      // 256 chunks of 8 bf16, own 16 rows
            const int row = row0 + (idx >> 4), chunk = idx & 15, col = chunk << 3;
            uint4 val = make_uint4(0u, 0u, 0u, 0u);
            if (n0 + row < NN)
                val = *(const uint4*)&x[(size_t)(n0 + row) * CC + col];
            *(uint4*)((char*)A + ASWZ(row, chunk)) = val;
        }
    }
    // same-wave LDS ordering: no barrier needed

    { // LN1: lane handles node row0+(lane&15), quarter (lane>>4)*32 cols
        const int nd = row0 + (lane & 15), qd = lane >> 4;
        float vals[32];
        #pragma unroll
        for (int i = 0; i < 4; ++i){
            uint4 u = *(const uint4*)((const char*)A + ASWZ(nd, (qd << 2) + i));
            unsigned uu[4] = {u.x, u.y, u.z, u.w};
            #pragma unroll
            for (int j2 = 0; j2 < 4; ++j2){
                vals[i*8 + j2*2]     = u2f((unsigned short)(uu[j2] & 0xFFFF));
                vals[i*8 + j2*2 + 1] = u2f((unsigned short)(uu[j2] >> 16));
            }
        }
        float s = 0.f;
        #pragma unroll
        for (int i = 0; i < 32; ++i) s += vals[i];
        s += __shfl_xor(s, 16); s += __shfl_xor(s, 32);
        const float mu = s * (1.0f / CC);
        float vv = 0.f;
        #pragma unroll
        for (int i = 0; i < 32; ++i){ const float d = vals[i] - mu; vv += d * d; }
        vv += __shfl_xor(vv, 16); vv += __shfl_xor(vv, 32);
        const float rstd = rsqrtf(vv * (1.0f / CC) + 1e-5f);
        #pragma unroll
        for (int i = 0; i < 4; ++i){
            unsigned w[4];
            #pragma unroll
            for (int j2 = 0; j2 < 4; ++j2){
                const int c0 = qd * 32 + i * 8 + j2 * 2;
                const float a0 = (vals[i*8+j2*2]   - mu) * rstd * b2f(g[c0])   + b2f(bb[c0]);
                const float a1 = (vals[i*8+j2*2+1] - mu) * rstd * b2f(g[c0+1]) + b2f(bb[c0+1]);
                w[j2] = (unsigned)f2u(a0) | ((unsigned)f2u(a1) << 16);
            }
            *(uint4*)((char*)A + ASWZ(nd, (qd << 2) + i)) = make_uint4(w[0], w[1], w[2], w[3]);
        }
    }
    // same-wave LDS ordering: no barrier needed

    gemm_nodes_128(A, row0, lane, WFq, bq, q,  n0);
    gemm_nodes_128(A, row0, lane, WFk, bk, k,  n0);
    gemm_nodes_128(A, row0, lane, WFv, bv, v,  n0);
    gemm_nodes_128(A, row0, lane, WFs, bs, xr, n0);
}

// ---------------- CSR scan ----------------
__global__ __launch_bounds__(1024) void k_scan1(const int* __restrict__ deg,
                                                int* __restrict__ row, int* __restrict__ bsum){
    __shared__ int sb[1024];
    const int t = threadIdx.x;
    const int idx = blockIdx.x * 1024 + t;
    sb[t] = (idx < NN) ? deg[idx] : 0;
    __syncthreads();
    for (int off = 1; off < 1024; off <<= 1){
        int tv = (t >= off) ? sb[t - off] : 0;
        __syncthreads();
        sb[t] += tv;
        __syncthreads();
    }
    if (idx < NN) row[idx + 1] = sb[t];
    if (t == 1023) bsum[blockIdx.x] = sb[1023];
}

// adds prefix of block sums + initializes the scatter cursor to rowstart
__global__ __launch_bounds__(1024) void k_scan3(const int* __restrict__ bsum,
                                                int* __restrict__ row, int* __restrict__ cur){
    __shared__ int sadd;
    const int t = threadIdx.x;
    if (t < 64){
        int a = 0;
        for (int i = t; i < (int)blockIdx.x; i += 64) a += bsum[i];
        for (int off = 32; off; off >>= 1) a += __shfl_xor(a, off);
        if (t == 0) sadd = a;
    }
    __syncthreads();
    const int idx = blockIdx.x * 1024 + t;
    if (idx < NN){
        const int vfin = row[idx + 1] + sadd;
        row[idx + 1] = vfin;
        cur[idx + 1] = vfin;
    }
    if (idx == 0){ row[0] = 0; cur[0] = 0; }
}

// ---------------- kernel B: MFMA E-GEMM + alpha + ea/src CSR-pack + passthrough ------
// V-path factored out: writes eaperm (64ch bf16) + srcperm instead of vperm (128ch).
__global__ __launch_bounds__(256) void k_edge6(
    const void* __restrict__ ea_raw, const int* __restrict__ flags,
    const bf16* __restrict__ WFe, const bf16* __restrict__ be,
    const bf16* __restrict__ kv_q, const bf16* __restrict__ kv_k,
    const int* __restrict__ srcI, const int* __restrict__ dstI, int* __restrict__ cur,
    unsigned short* __restrict__ alphap, unsigned short* __restrict__ eaperm,
    int* __restrict__ srcperm, void* __restrict__ outv)
{
    __shared__ unsigned short EA[64 * 64];    // 8 KB, ea tile bf16, swizzled
    __shared__ unsigned short ET[64 * 128];   // 16 KB, E tile bf16, swizzled
    const int t = threadIdx.x, lane = t & 63, wid = t >> 6;
    const int e0 = blockIdx.x * 64;
    const int row0 = wid * 16;

    // stage own 16 ea rows -> LDS (bf16) + fused raw passthrough write
    if (flags[0]){
        const float* ea = (const float*)ea_raw;
        float* outd = (float*)outv + (size_t)NN * CC;
        #pragma unroll
        for (int it = 0; it < 4; ++it){
            const int idx = lane + 64 * it;      // 256 units of 4 ch, own 16 rows
            const int row = row0 + (idx >> 4), c = (idx & 15) << 2;
            const size_t o = (size_t)(e0 + row) * EDIM + c;
            const float4 a = *(const float4*)&ea[o];
            *(float4*)&outd[o] = a;              // fused passthrough copy
            ushort4 b;
            b.x = f2u(a.x); b.y = f2u(a.y); b.z = f2u(a.z); b.w = f2u(a.w);
            *(ushort4*)((char*)EA + EASWZ(row, c >> 3) + ((c & 7) << 1)) = b;
        }
    } else {
        const unsigned short* ea = (const unsigned short*)ea_raw;
        unsigned short* outd = (unsigned short*)outv + (size_t)NN * CC;
        #pragma unroll
        for (int it = 0; it < 2; ++it){
            const int idx = lane + 64 * it;      // 128 units of 8 ch, own 16 rows
            const int row = row0 + (idx >> 3), c = (idx & 7) << 3;
            const size_t o = (size_t)(e0 + row) * EDIM + c;
            uint4 raw = *(const uint4*)&ea[o];
            *(uint4*)&outd[o] = raw;             // fused passthrough copy
            *(uint4*)((char*)EA + EASWZ(row, c >> 3)) = raw;
        }
    }
    // same-wave LDS ordering: no barrier needed

    // E-GEMM: wave wid computes edge-rows row0..row0+15 x 128 ch (K=64 -> 2 k-steps)
    {
        const int rA = row0 + (lane & 15);
        sh8 af[2];
        #pragma unroll
        for (int ks = 0; ks < 2; ++ks)
            af[ks] = *(const sh8*)((const char*)EA + EASWZ(rA, (ks << 2) + (lane >> 4)));
        f32x4 acc[8] = {};
        #pragma unroll
        for (int ks = 0; ks < 2; ++ks)
            #pragma unroll
            for (int ct = 0; ct < 8; ++ct){
                sh8 bfr = *(const sh8*)(WFe + ((size_t)((ct << 1) + ks) * 64 + lane) * 8);
                acc[ct] = __builtin_amdgcn_mfma_f32_16x16x32_bf16(af[ks], bfr, acc[ct], 0, 0, 0);
            }
        #pragma unroll
        for (int ct = 0; ct < 8; ++ct){
            const int c = (ct << 4) + (lane & 15);
            const float bv = b2f(be[c]);
            #pragma unroll
            for (int i = 0; i < 4; ++i){
                const int r = row0 + ((lane >> 4) << 2) + i;
                *(unsigned short*)((char*)ET + ASWZ(r, c >> 3) + ((c & 7) << 1)) =
                    f2u(acc[ct][i] + bv);
            }
        }
    }
    // same-wave LDS ordering: no barrier needed (pack reads own rows)

    // pack: thread handles 8 edges x 4 ch; fused atomic scatter + batched gathers (ILP)
    const int g = t >> 5, cT = t & 31, c = cT << 2;
    int s8[8], d8[8];
    #pragma unroll
    for (int i = 0; i < 8; ++i){
        const int eid = e0 + g * 8 + i;
        s8[i] = srcI[eid];
        d8[i] = dstI[eid];
    }
    // fused scatter: lanes cT<8 claim the CSR slot for edge cT of this group
    int pmine = 0;
    if (cT < 8) pmine = atomicAdd(&cur[dstI[e0 + g * 8 + cT]], 1);
    int p8[8];
    #pragma unroll
    for (int i = 0; i < 8; ++i)
        p8[i] = __shfl(pmine, ((g & 1) << 5) + i);

    ushort4 kr[8], qr[8];
    #pragma unroll
    for (int i = 0; i < 8; ++i) kr[i] = *(const ushort4*)&kv_k[(size_t)s8[i] * CC + c];
    #pragma unroll
    for (int i = 0; i < 8; ++i) qr[i] = *(const ushort4*)&kv_q[(size_t)d8[i] * CC + c];
    #pragma unroll
    for (int i = 0; i < 8; ++i){
        const ushort4 ev = *(const ushort4*)((const char*)ET + ASWZ(g * 8 + i, c >> 3) + ((c & 7) << 1));
        const float e0_ = u2f(ev.x), e1_ = u2f(ev.y), e2_ = u2f(ev.z), e3_ = u2f(ev.w);
        // alpha partial: q . (k + e) over this thread's 4 channels
        float part = u2f(qr[i].x) * (e0_ + u2f(kr[i].x)) + u2f(qr[i].y) * (e1_ + u2f(kr[i].y))
                   + u2f(qr[i].z) * (e2_ + u2f(kr[i].z)) + u2f(qr[i].w) * (e3_ + u2f(kr[i].w));
        part += __shfl_xor(part, 1);
        part += __shfl_xor(part, 2);           // full 16-ch head dot across 4 lanes
        if ((cT & 3) == 0)
            alphap[(size_t)p8[i] * 8 + (cT >> 2)] = f2u(part * 0.25f);   // 1/sqrt(16)
        // eaperm: 16 lanes x 4 ch cover the 64-ch bf16 ea row (from LDS tile)
        if (cT < 16){
            const int c2 = cT << 2;
            ushort4 er = *(const ushort4*)((const char*)EA + EASWZ(g * 8 + i, c2 >> 3) + ((c2 & 7) << 1));
            *(ushort4*)&eaperm[(size_t)p8[i] * EDIM + c2] = er;
        }
        if (cT == 16) srcperm[p8[i]] = s8[i];
    }
}

// ---------------- kernel C: per-node softmax + factored E reconstruction ----------
// out = (Σp·v[src] + (Σp·ea)@we)/den + (den/den+eps)·be
__global__ __launch_bounds__(256) void k_attn4(
    const unsigned short* __restrict__ alphap, const unsigned short* __restrict__ eaperm,
    const int* __restrict__ srcperm, const bf16* __restrict__ vC,
    const void* __restrict__ we_raw, const bf16* __restrict__ be,
    const int* __restrict__ flags, const int* __restrict__ rowstart,
    bf16* __restrict__ attn_bf)
{
    __shared__ unsigned short weS[EDIM * CC];   // 16 KB bf16
    __shared__ float sea[4][8][68];             // 8.7 KB, padded rows
    const int t = threadIdx.x, lane = t & 63, wid = t >> 6;

    if (flags[0]){
        const float* wr = (const float*)we_raw;
        for (int i = t; i < EDIM * CC; i += 256) weS[i] = f2u(wr[i]);
    } else {
        const unsigned short* wr = (const unsigned short*)we_raw;
        for (int i = t; i < EDIM * CC; i += 256) weS[i] = wr[i];
    }
    __syncthreads();

    const int n = blockIdx.x * 4 + wid;
    const int h = lane >> 3, sub = lane & 7;

    float m = -INFINITY, den = 0.0f;
    float num0 = 0.f, num1 = 0.f;
    float sA[8] = {0.f, 0.f, 0.f, 0.f, 0.f, 0.f, 0.f, 0.f};

    const int jb = rowstart[n], je = rowstart[n + 1];
    for (int j = jb; j < je; ++j) {
        const float alpha = u2f(alphap[(size_t)j * 8 + h]);
        const int s = srcperm[j];
        const float2 v2 = loadbf2(&vC[(size_t)s * CC + 2 * lane]);
        const ushort4 ew0 = *(const ushort4*)&eaperm[(size_t)j * EDIM + sub * 8];
        const ushort4 ew1 = *(const ushort4*)&eaperm[(size_t)j * EDIM + sub * 8 + 4];
        if (alpha > m) {
            const float sc = __expf(m - alpha);
            den *= sc; num0 *= sc; num1 *= sc;
            #pragma unroll
            for (int i = 0; i < 8; ++i) sA[i] *= sc;
            m = alpha;
        }
        const float p = __expf(alpha - m);
        den += p;
        num0 += p * v2.x;
        num1 += p * v2.y;
        sA[0] += p * u2f(ew0.x); sA[1] += p * u2f(ew0.y);
        sA[2] += p * u2f(ew0.z); sA[3] += p * u2f(ew0.w);
        sA[4] += p * u2f(ew1.x); sA[5] += p * u2f(ew1.y);
        sA[6] += p * u2f(ew1.z); sA[7] += p * u2f(ew1.w);
    }
    // publish this lane's 8 ea-dims (same-wave rows: no barrier)
    #pragma unroll
    for (int i = 0; i < 8; ++i) sea[wid][h][sub * 8 + i] = sA[i];

    const float inv = 1.0f / (den + 1e-16f);
    const float sw  = den * inv;               // Σw (0 for zero-degree nodes)

    // finalize channels c0=2*lane, c1=2*lane+1 (head h)
    const int c0 = 2 * lane, c1 = 2 * lane + 1;
    float accE0 = 0.f, accE1 = 0.f;
    #pragma unroll 8
    for (int d = 0; d < EDIM; ++d){
        const float S = sea[wid][h][d];
        accE0 += S * u2f(weS[d * CC + c0]);
        accE1 += S * u2f(weS[d * CC + c1]);
    }
    __hip_bfloat162 pr;
    pr.x = f2b((num0 + accE0) * inv + sw * b2f(be[c0]));
    pr.y = f2b((num1 + accE1) * inv + sw * b2f(be[c1]));
    *reinterpret_cast<__hip_bfloat162*>(&attn_bf[(size_t)n * CC + 2 * lane]) = pr;
}

// ---------------- kernel D: proj + residual + LN2 + MLP + residual (MFMA) ----------------
__global__ __launch_bounds__(256) void k_post2(
    const bf16* __restrict__ attn_bf, const bf16* __restrict__ xr,
    const void* __restrict__ x_raw,
    const bf16* __restrict__ WFp, const bf16* __restrict__ bp,
    const bf16* __restrict__ WF1, const bf16* __restrict__ b1,
    const bf16* __restrict__ WF2, const bf16* __restrict__ b2c,
    const bf16* __restrict__ g2, const bf16* __restrict__ bb2,
    void* __restrict__ outv, const int* __restrict__ flags)
{
    __shared__ unsigned short A[64 * 128];     // 16 KB
    __shared__ unsigned short HID[64 * 512];   // 64 KB
    const int t = threadIdx.x, lane = t & 63, wid = t >> 6;
    const int n0 = blockIdx.x * 64;
    const int f32io = flags[0];
    const int row0 = wid * 16;

    #pragma unroll
    for (int it = 0; it < 4; ++it){
        const int idx = lane + 64 * it;          // 256 chunks of 8 bf16, own 16 rows
        const int row = row0 + (idx >> 4), chunk = idx & 15, col = chunk << 3;
        unsigned w[4] = {0u, 0u, 0u, 0u};
        if (n0 + row < NN){
            const size_t o = (size_t)(n0 + row) * CC + col;
            uint4 a4 = *(const uint4*)&attn_bf[o];
            uint4 r4 = *(const uint4*)&xr[o];
            unsigned au[4] = {a4.x, a4.y, a4.z, a4.w};
            unsigned ru[4] = {r4.x, r4.y, r4.z, r4.w};
            #pragma unroll
            for (int j2 = 0; j2 < 4; ++j2){
                const float lo = u2f((unsigned short)(au[j2] & 0xFFFF)) +
                                 u2f((unsigned short)(ru[j2] & 0xFFFF));
                const float hi = u2f((unsigned short)(au[j2] >> 16)) +
                                 u2f((unsigned short)(ru[j2] >> 16));
                w[j2] = (unsigned)f2u(lo) | ((unsigned)f2u(hi) << 16);
            }
        }
        *(uint4*)((char*)A + ASWZ(row, chunk)) = make_uint4(w[0], w[1], w[2], w[3]);
    }
    // same-wave LDS ordering: no barrier needed

    const int rA = row0 + (lane & 15);

    float out2[8][4];
    {
        sh8 af[4];
        #pragma unroll
        for (int ks = 0; ks < 4; ++ks)
            af[ks] = *(const sh8*)((const char*)A + ASWZ(rA, (ks << 2) + (lane >> 4)));
        f32x4 acc[8] = {};
        #pragma unroll
        for (int ks = 0; ks < 4; ++ks)
            #pragma unroll
            for (int ct = 0; ct < 8; ++ct){
                sh8 bfr = *(const sh8*)(WFp + ((size_t)((ct << 2) + ks) * 64 + lane) * 8);
                acc[ct] = __builtin_amdgcn_mfma_f32_16x16x32_bf16(af[ks], bfr, acc[ct], 0, 0, 0);
            }
        #pragma unroll
        for (int ct = 0; ct < 8; ++ct){
            const int c = (ct << 4) + (lane & 15);
            const float bv = b2f(bp[c]);
            #pragma unroll
            for (int i = 0; i < 4; ++i){
                const int r = row0 + ((lane >> 4) << 2) + i;
                float xs = 0.f;
                if (n0 + r < NN){
                    const size_t o = (size_t)(n0 + r) * CC + c;
                    xs = f32io ? ((const float*)x_raw)[o] : b2f(((const bf16*)x_raw)[o]);
                }
                out2[ct][i] = acc[ct][i] + bv + xs;
            }
        }
    }

    { // LN2 in registers, write normalized bf16 -> A (same-wave rows only)
        float mu[4], rstd[4];
        #pragma unroll
        for (int i = 0; i < 4; ++i){
            float s = 0.f;
            #pragma unroll
            for (int ct = 0; ct < 8; ++ct) s += out2[ct][i];
            s += __shfl_xor(s, 1); s += __shfl_xor(s, 2);
            s += __shfl_xor(s, 4); s += __shfl_xor(s, 8);
            mu[i] = s * (1.0f / CC);
        }
        #pragma unroll
        for (int i = 0; i < 4; ++i){
            float vv = 0.f;
            #pragma unroll
            for (int ct = 0; ct < 8; ++ct){ const float d = out2[ct][i] - mu[i]; vv += d * d; }
            vv += __shfl_xor(vv, 1); vv += __shfl_xor(vv, 2);
            vv += __shfl_xor(vv, 4); vv += __shfl_xor(vv, 8);
            rstd[i] = rsqrtf(vv * (1.0f / CC) + 1e-5f);
        }
        #pragma unroll
        for (int ct = 0; ct < 8; ++ct){
            const int c = (ct << 4) + (lane & 15);
            const float gv = b2f(g2[c]), bbv = b2f(bb2[c]);
            const int chunk = c >> 3;
            #pragma unroll
            for (int i = 0; i < 4; ++i){
                const int r = row0 + ((lane >> 4) << 2) + i;
                const float ln = (out2[ct][i] - mu[i]) * rstd[i] * gv + bbv;
                *(unsigned short*)((char*)A + ASWZ(r, chunk) + ((c & 7) << 1)) = f2u(ln);
            }
        }
    }

    { // GEMM2: hid = gelu(LN2 @ w1 + b1) -> HID
        sh8 af[4];
        #pragma unroll
        for (int ks = 0; ks < 4; ++ks)
            af[ks] = *(const sh8*)((const char*)A + ASWZ(rA, (ks << 2) + (lane >> 4)));
        #pragma unroll
        for (int grp = 0; grp < 4; ++grp){
            f32x4 acc[8] = {};
            #pragma unroll
            for (int ks = 0; ks < 4; ++ks)
                #pragma unroll
                for (int ctl = 0; ctl < 8; ++ctl){
                    const int ct = grp * 8 + ctl;
                    sh8 bfr = *(const sh8*)(WF1 + ((size_t)((ct << 2) + ks) * 64 + lane) * 8);
                    acc[ctl] = __builtin_amdgcn_mfma_f32_16x16x32_bf16(af[ks], bfr, acc[ctl], 0, 0, 0);
                }
            #pragma unroll
            for (int ctl = 0; ctl < 8; ++ctl){
                const int ct = grp * 8 + ctl;
                const int c = (ct << 4) + (lane & 15);
                const float bv = b2f(b1[c]);
                const int chunk = c >> 3;
                #pragma unroll
                for (int i = 0; i < 4; ++i){
                    const int r = row0 + ((lane >> 4) << 2) + i;
                    const float h = gelu_tanh(acc[ctl][i] + bv);
                    *(unsigned short*)((char*)HID + HSWZ(r, chunk) + ((c & 7) << 1)) = f2u(h);
                }
            }
        }
    }

    { // GEMM3: o = hid @ w2 ; final = out2 + o + b2
        f32x4 acc[8] = {};
        #pragma unroll
        for (int ks = 0; ks < 16; ++ks){
            sh8 afh = *(const sh8*)((const char*)HID + HSWZ(rA, (ks << 2) + (lane >> 4)));
            #pragma unroll
            for (int ct = 0; ct < 8; ++ct){
                sh8 bfr = *(const sh8*)(WF2 + ((size_t)((ct << 4) + ks) * 64 + lane) * 8);
                acc[ct] = __builtin_amdgcn_mfma_f32_16x16x32_bf16(afh, bfr, acc[ct], 0, 0, 0);
            }
        }
        #pragma unroll
        for (int ct = 0; ct < 8; ++ct){
            const int c = (ct << 4) + (lane & 15);
            const float bv = b2f(b2c[c]);
            #pragma unroll
            for (int i = 0; i < 4; ++i){
                const int r = row0 + ((lane >> 4) << 2) + i;
                if (n0 + r < NN){
                    const float val = out2[ct][i] + acc[ct][i] + bv;
                    if (f32io) ((float*)outv)[(size_t)(n0 + r) * CC + c] = val;
                    else       ((bf16*)outv)[(size_t)(n0 + r) * CC + c] = f2b(val);
                }
            }
        }
    }
}

extern "C" void kernel_launch(void* const* d_in, const int* in_sizes, int n_in,
                              void* d_out, int out_size, void* d_ws, size_t ws_size,
                              hipStream_t stream)
{
    if (ws_size < WS_NEED) {
        fprintf(stderr, "[kl] WS TOO SMALL ws=%zu need=%zu\n", ws_size, WS_NEED);
        return;
    }

    char* ws = (char*)d_ws;
    int*  flags = (int*)(ws + OFF_FLAG);
    int*  deg   = (int*)(ws + OFF_DEG);
    int*  row   = (int*)(ws + OFF_ROW);
    int*  cur   = (int*)(ws + OFF_CUR);
    int*  srcI  = (int*)(ws + OFF_SRC);
    int*  dstI  = (int*)(ws + OFF_DST);
    int*  bsum  = (int*)(ws + OFF_BSUM);
    bf16* qC    = (bf16*)(ws + OFF_QC);
    bf16* kC    = (bf16*)(ws + OFF_KC);
    bf16* vC    = (bf16*)(ws + OFF_VC);
    bf16* attC  = (bf16*)(ws + OFF_ATT);
    bf16* xrC   = (bf16*)(ws + OFF_XRC);
    unsigned short* alphap = (unsigned short*)(ws + OFF_ALP);
    unsigned short* eaperm = (unsigned short*)(ws + OFF_EAP);
    int*  srcperm = (int*)(ws + OFF_SP);
    bf16* WFq = (bf16*)(ws + OFF_WFQ);
    bf16* WFk = (bf16*)(ws + OFF_WFK);
    bf16* WFv = (bf16*)(ws + OFF_WFV);
    bf16* WFs = (bf16*)(ws + OFF_WFS);
    bf16* WFp = (bf16*)(ws + OFF_WFP);
    bf16* WF1 = (bf16*)(ws + OFF_WF1);
    bf16* WF2 = (bf16*)(ws + OFF_WF2);
    bf16* WFe = (bf16*)(ws + OFF_WFE);

    bf16* P = (bf16*)(ws + OFF_PRM);
    bf16 *bqC=P; P+=128; bf16 *bkC=P; P+=128;
    bf16 *bvC=P; P+=128; bf16 *bsC=P; P+=128;
    bf16 *beC=P; P+=128; bf16 *bpC=P; P+=128;
    bf16 *b1C=P; P+=512; bf16 *b2C=P; P+=128;
    bf16 *g1C=P; P+=128; bf16 *n1C=P; P+=128;
    bf16 *g2C=P; P+=128; bf16 *n2C=P; P+=128;

    hipMemsetAsync(deg, 0, (size_t)(NN + 1) * sizeof(int), stream);

    // 1) detect dtypes
    k_detect<<<1, 256, 0, stream>>>((const unsigned short*)d_in[0],
                                    (const unsigned int*)d_in[2], flags);

    // 2) canonicalize biases/LN (tiny) + indices (+deg histogram fused)
    {
        CvtJobs cj;
        bf16* dsts[12] = {bqC,bkC,bvC,bsC,beC,bpC,b1C,b2C,g1C,n1C,g2C,n2C};
        const int idxs[12] = {4,6,8,10,12,14,16,18,19,20,21,22};
        const int ns[12]   = {128,128,128,128,128,128,512,128,128,128,128,128};
        for (int i = 0; i < 12; ++i){ cj.j[i].s = d_in[idxs[i]]; cj.j[i].d = dsts[i]; cj.j[i].n = ns[i]; }
        k_cvt_all<<<12 * 2, 256, 0, stream>>>(cj, flags);
    }
    k_cvt_idx<<<1024, 256, 0, stream>>>((const int*)d_in[2], srcI, dstI, deg, flags);

    // 3) weight fragment pre-transform straight from RAW inputs (one launch, 8 jobs)
    {
        WJobs wj;
        const WJob js[8] = {{d_in[3],WFq,128,128},{d_in[5],WFk,128,128},{d_in[7],WFv,128,128},
                            {d_in[9],WFs,128,128},{d_in[13],WFp,128,128},{d_in[15],WF1,128,512},
                            {d_in[17],WF2,512,128},{d_in[11],WFe,64,128}};
        for (int i = 0; i < 8; ++i) wj.j[i] = js[i];
        k_wprep_all<<<8 * 48, 256, 0, stream>>>(wj, flags);
    }

    // 4) pipeline
    const int NB64 = (NN + 63) / 64;
    const int NSC  = (NN + 1023) / 1024;
    k_node_pre2<<<NB64, 256, 0, stream>>>(d_in[0], flags, WFq, bqC, WFk, bkC, WFv, bvC,
                                          WFs, bsC, g1C, n1C, qC, kC, vC, xrC);
    k_scan1<<<NSC, 1024, 0, stream>>>(deg, row, bsum);
    k_scan3<<<NSC, 1024, 0, stream>>>(bsum, row, cur);
    k_edge6<<<NE / 64, 256, 0, stream>>>(d_in[1], flags, WFe, beC, qC, kC,
                                         srcI, dstI, cur, alphap, eaperm, srcperm, d_out);
    k_attn4<<<NN / 4, 256, 0, stream>>>(alphap, eaperm, srcperm, vC, d_in[11], beC,
                                        flags, row, attC);
    k_post2<<<NB64, 256, 0, stream>>>(attC, xrC, d_in[0], WFp, bpC, WF1, b1C, WF2, b2C,
                                      g2C, n2C, d_out, flags);
}

// Round 15
// 501.488 us; speedup vs baseline: 1.1423x; 1.1423x over previous
//
#include <hip/hip_runtime.h>
#include <hip/hip_bf16.h>
#include <cstdio>

#define NN 50000
#define NE 800000
#define CC 128
#define EDIM 64
#define HIDN 512

using bf16 = __hip_bfloat16;
typedef short sh8 __attribute__((ext_vector_type(8)));
typedef float f32x4 __attribute__((ext_vector_type(4)));

static __device__ __forceinline__ float b2f(bf16 v){ return __bfloat162float(v); }
static __device__ __forceinline__ bf16 f2b(float v){ return __float2bfloat16(v); }
static __device__ __forceinline__ float u2f(unsigned short u){
    union { unsigned int i; float f; } w; w.i = ((unsigned int)u) << 16; return w.f;
}
static __device__ __forceinline__ unsigned short f2u(float f){
    bf16 b = __float2bfloat16(f);
    return *reinterpret_cast<unsigned short*>(&b);
}
static __device__ __forceinline__ float2 loadbf2(const bf16* p){
    __hip_bfloat162 v = *reinterpret_cast<const __hip_bfloat162*>(p);
    return make_float2(__bfloat162float(v.x), __bfloat162float(v.y));
}
static __device__ __forceinline__ float gelu_tanh(float x){
    const float c = 0.7978845608028654f; // sqrt(2/pi)
    float u = c * (x + 0.044715f * x * x * x);
    return x / (1.0f + __expf(-2.0f * u));   // x*sigmoid(2u) == 0.5x(1+tanh(u))
}

// ---------------- workspace layout ----------------
constexpr size_t AL(size_t x){ return (x + 255) & ~(size_t)255; }
constexpr size_t OFF_FLAG = 0;                                   // int[16]
constexpr size_t OFF_DEG  = 256;
constexpr size_t OFF_ROW  = AL(OFF_DEG + (size_t)(NN + 1) * 4);
constexpr size_t OFF_CUR  = AL(OFF_ROW + (size_t)(NN + 1) * 4); // NN+1 ints
constexpr size_t OFF_SRC  = AL(OFF_CUR + (size_t)(NN + 1) * 4);
constexpr size_t OFF_DST  = AL(OFF_SRC + (size_t)NE * 4);
constexpr size_t OFF_QC   = AL(OFF_DST + (size_t)NE * 4);
constexpr size_t OFF_KC   = AL(OFF_QC  + (size_t)NN * CC * 2);
constexpr size_t OFF_VC   = AL(OFF_KC  + (size_t)NN * CC * 2);
constexpr size_t OFF_ATT  = AL(OFF_VC  + (size_t)NN * CC * 2);
constexpr size_t OFF_PRM  = AL(OFF_ATT + (size_t)NN * CC * 2);   // biases/LN only
constexpr size_t PRM_ELEMS = 4096;
constexpr size_t OFF_ALP  = AL(OFF_PRM + PRM_ELEMS * 2);         // alpha: E*8 bf16
constexpr size_t OFF_VP   = AL(OFF_ALP + (size_t)NE * 8 * 2);
constexpr size_t OFF_XRC  = AL(OFF_VP + (size_t)NE * CC * 2);
constexpr size_t OFF_WFQ  = AL(OFF_XRC + (size_t)NN * CC * 2);
constexpr size_t OFF_WFK  = OFF_WFQ + 32768;
constexpr size_t OFF_WFV  = OFF_WFK + 32768;
constexpr size_t OFF_WFS  = OFF_WFV + 32768;
constexpr size_t OFF_WFP  = OFF_WFS + 32768;
constexpr size_t OFF_WF1  = OFF_WFP + 32768;
constexpr size_t OFF_WF2  = OFF_WF1 + 131072;
constexpr size_t OFF_WFE  = OFF_WF2 + 131072;    // we fragment-linear, 16 KB
constexpr size_t OFF_BSUM = OFF_WFE + 16384;     // 64 ints
constexpr size_t WS_NEED  = OFF_BSUM + 256;

// ---------------- dtype detection ----------------
__global__ void k_detect(const unsigned short* xw, const unsigned int* ew, int* flags){
    __shared__ int sw, sz;
    if (threadIdx.x == 0){ sw = 0; sz = 0; }
    __syncthreads();
    int w = 0;
    for (int i = threadIdx.x; i < 8192; i += 256){
        unsigned e = (xw[i] >> 7) & 0xFF;
        if (e == 0xFF || (e != 0 && (e < 0x60 || e > 0x90))) w++;
    }
    atomicAdd(&sw, w);
    int z = 0;
    for (int i = threadIdx.x; i < 2048; i += 256)
        if (ew[2*i+1] == 0u) z++;
    atomicAdd(&sz, z);
    __syncthreads();
    if (threadIdx.x == 0){
        flags[0] = (sw > 2048) ? 1 : 0;   // 1: floats are f32 on device
        flags[1] = (sz > 1536) ? 1 : 0;   // 1: edge_index is int64 on device
    }
}

// ---------------- canonicalizers (biases / LN params only) ----------------
struct CvtJob { const void* s; bf16* d; int n; };
struct CvtJobs { CvtJob j[12]; };
__global__ void k_cvt_all(CvtJobs jobs, const int* flags){
    const int f = flags[0];
    const int e = blockIdx.x >> 1;           // 2 blocks per entry
    const CvtJob J = jobs.j[e];
    const int stride = 2 * 256;
    for (int i = (blockIdx.x & 1) * 256 + threadIdx.x; i < J.n; i += stride){
        if (f) J.d[i] = f2b(((const float*)J.s)[i]);
        else   J.d[i] = ((const bf16*)J.s)[i];
    }
}

// indices + degree histogram in one pass
__global__ void k_cvt_idx(const int* e32, int* srcI, int* dstI, int* deg, const int* flags){
    const int f = flags[1];
    int i = blockIdx.x * blockDim.x + threadIdx.x;
    const int stride = gridDim.x * blockDim.x;
    if (f){
        const long long* e64 = (const long long*)e32;
        for (; i < NE; i += stride){
            srcI[i] = (int)e64[i];
            const int d = (int)e64[NE + i];
            dstI[i] = d;
            atomicAdd(&deg[d], 1);
        }
    } else {
        for (; i < NE; i += stride){
            srcI[i] = e32[i];
            const int d = e32[NE + i];
            dstI[i] = d;
            atomicAdd(&deg[d], 1);
        }
    }
}

// ---------------- weight fragment-linear pre-transform (reads RAW inputs) ----------
// WF[((ct*KS+ks)*64+lane)*8+j] = W[ks*32+(lane>>4)*8+j][ct*16+(lane&15)]
struct WJob { const void* W; bf16* WF; int K; int N; };
struct WJobs { WJob j[8]; };
__global__ void k_wprep_all(WJobs jobs, const int* flags){
    const int f = flags[0];
    const WJob J = jobs.j[blockIdx.x / 48];
    const int KS = J.K >> 5;
    const int total = J.K * J.N;
    for (int o = (blockIdx.x % 48) * 256 + threadIdx.x; o < total; o += 48 * 256){
        const int j  = o & 7;
        const int ln = (o >> 3) & 63;
        const int tt = o >> 9;
        const int ks = tt % KS, ct = tt / KS;
        const int kk = (ks << 5) + ((ln >> 4) << 3) + j;
        const int c  = (ct << 4) + (ln & 15);
        const int src = kk * J.N + c;
        J.WF[o] = f ? f2b(((const float*)J.W)[src]) : ((const bf16*)J.W)[src];
    }
}

// swizzled LDS addressing, 16B chunks XORed with low row bits
#define ASWZ(row, chunk)  (((row) << 8)  + ((((chunk) ^ ((row) & 15))) << 4))   // 256B rows
#define HSWZ(row, chunk)  (((row) << 10) + ((((chunk) ^ ((row) & 15))) << 4))   // 1024B rows
#define EASWZ(row, chunk) (((row) << 7)  + ((((chunk) ^ ((row) & 7)))  << 4))   // 128B rows

// one [16 x 128] row-tile times fragment-linear W[128x128], bias add, bf16 store
static __device__ __forceinline__ void gemm_nodes_128(
    const unsigned short* Abase, int row0, int lane,
    const bf16* __restrict__ WF, const bf16* __restrict__ bias,
    bf16* __restrict__ outp, int n0)
{
    const int rA = row0 + (lane & 15);
    sh8 af[4];
    #pragma unroll
    for (int ks = 0; ks < 4; ++ks)
        af[ks] = *(const sh8*)((const char*)Abase + ASWZ(rA, (ks << 2) + (lane >> 4)));
    f32x4 acc[8] = {};
    #pragma unroll
    for (int ks = 0; ks < 4; ++ks)
        #pragma unroll
        for (int ct = 0; ct < 8; ++ct){
            sh8 bfr = *(const sh8*)(WF + ((size_t)((ct << 2) + ks) * 64 + lane) * 8);
            acc[ct] = __builtin_amdgcn_mfma_f32_16x16x32_bf16(af[ks], bfr, acc[ct], 0, 0, 0);
        }
    #pragma unroll
    for (int ct = 0; ct < 8; ++ct){
        const int c = (ct << 4) + (lane & 15);
        const float bv = b2f(bias[c]);
        #pragma unroll
        for (int i = 0; i < 4; ++i){
            const int r = row0 + ((lane >> 4) << 2) + i;
            if (n0 + r < NN)
                outp[(size_t)(n0 + r) * CC + c] = f2b(acc[ct][i] + bv);
        }
    }
}

// ---------------- kernel A: LN1 + q/k/v/xr MFMA GEMMs (64 nodes/block) ----------------
// Barrier-free: each wave stages, LNs and GEMMs exactly its own 16 rows.
__global__ __launch_bounds__(256) void k_node_pre2(
    const void* __restrict__ x_raw, const int* __restrict__ flags,
    const bf16* __restrict__ WFq, const bf16* __restrict__ bq,
    const bf16* __restrict__ WFk, const bf16* __restrict__ bk,
    const bf16* __restrict__ WFv, const bf16* __restrict__ bv,
    const bf16* __restrict__ WFs, const bf16* __restrict__ bs,
    const bf16* __restrict__ g,  const bf16* __restrict__ bb,
    bf16* __restrict__ q, bf16* __restrict__ k, bf16* __restrict__ v,
    bf16* __restrict__ xr)
{
    __shared__ unsigned short A[64 * 128];      // 16 KB, swizzled
    const int t = threadIdx.x, lane = t & 63, wid = t >> 6;
    const int n0 = blockIdx.x * 64;
    const int row0 = wid * 16;

    if (flags[0]){
        const float* x = (const float*)x_raw;
        #pragma unroll
        for (int it = 0; it < 8; ++it){
            const int idx = lane + 64 * it;      // 512 units of 4 f32, own 16 rows
            const int row = row0 + (idx >> 5), c = (idx & 31) << 2;
            float4 a = make_float4(0.f, 0.f, 0.f, 0.f);
            if (n0 + row < NN)
                a = *(const float4*)&x[(size_t)(n0 + row) * CC + c];
            ushort4 b;
            b.x = f2u(a.x); b.y = f2u(a.y); b.z = f2u(a.z); b.w = f2u(a.w);
            *(ushort4*)((char*)A + ASWZ(row, c >> 3) + ((c & 7) << 1)) = b;
        }
    } else {
        const bf16* x = (const bf16*)x_raw;
        #pragma unroll
        for (int it = 0; it < 4; ++it){
            const int idx = lane + 64 * it;      // 256 chunks of 8 bf16, own 16 rows
            const int row = row0 + (idx >> 4), chunk = idx & 15, col = chunk << 3;
            uint4 val = make_uint4(0u, 0u, 0u, 0u);
            if (n0 + row < NN)
                val = *(const uint4*)&x[(size_t)(n0 + row) * CC + col];
            *(uint4*)((char*)A + ASWZ(row, chunk)) = val;
        }
    }
    // same-wave LDS ordering: no barrier needed

    { // LN1: lane handles node row0+(lane&15), quarter (lane>>4)*32 cols
        const int nd = row0 + (lane & 15), qd = lane >> 4;
        float vals[32];
        #pragma unroll
        for (int i = 0; i < 4; ++i){
            uint4 u = *(const uint4*)((const char*)A + ASWZ(nd, (qd << 2) + i));
            unsigned uu[4] = {u.x, u.y, u.z, u.w};
            #pragma unroll
            for (int j2 = 0; j2 < 4; ++j2){
                vals[i*8 + j2*2]     = u2f((unsigned short)(uu[j2] & 0xFFFF));
                vals[i*8 + j2*2 + 1] = u2f((unsigned short)(uu[j2] >> 16));
            }
        }
        float s = 0.f;
        #pragma unroll
        for (int i = 0; i < 32; ++i) s += vals[i];
        s += __shfl_xor(s, 16); s += __shfl_xor(s, 32);
        const float mu = s * (1.0f / CC);
        float vv = 0.f;
        #pragma unroll
        for (int i = 0; i < 32; ++i){ const float d = vals[i] - mu; vv += d * d; }
        vv += __shfl_xor(vv, 16); vv += __shfl_xor(vv, 32);
        const float rstd = rsqrtf(vv * (1.0f / CC) + 1e-5f);
        #pragma unroll
        for (int i = 0; i < 4; ++i){
            unsigned w[4];
            #pragma unroll
            for (int j2 = 0; j2 < 4; ++j2){
                const int c0 = qd * 32 + i * 8 + j2 * 2;
                const float a0 = (vals[i*8+j2*2]   - mu) * rstd * b2f(g[c0])   + b2f(bb[c0]);
                const float a1 = (vals[i*8+j2*2+1] - mu) * rstd * b2f(g[c0+1]) + b2f(bb[c0+1]);
                w[j2] = (unsigned)f2u(a0) | ((unsigned)f2u(a1) << 16);
            }
            *(uint4*)((char*)A + ASWZ(nd, (qd << 2) + i)) = make_uint4(w[0], w[1], w[2], w[3]);
        }
    }
    // same-wave LDS ordering: no barrier needed

    gemm_nodes_128(A, row0, lane, WFq, bq, q,  n0);
    gemm_nodes_128(A, row0, lane, WFk, bk, k,  n0);
    gemm_nodes_128(A, row0, lane, WFv, bv, v,  n0);
    gemm_nodes_128(A, row0, lane, WFs, bs, xr, n0);
}

// ---------------- CSR scan ----------------
__global__ __launch_bounds__(1024) void k_scan1(const int* __restrict__ deg,
                                                int* __restrict__ row, int* __restrict__ bsum){
    __shared__ int sb[1024];
    const int t = threadIdx.x;
    const int idx = blockIdx.x * 1024 + t;
    sb[t] = (idx < NN) ? deg[idx] : 0;
    __syncthreads();
    for (int off = 1; off < 1024; off <<= 1){
        int tv = (t >= off) ? sb[t - off] : 0;
        __syncthreads();
        sb[t] += tv;
        __syncthreads();
    }
    if (idx < NN) row[idx + 1] = sb[t];
    if (t == 1023) bsum[blockIdx.x] = sb[1023];
}

// adds prefix of block sums + initializes the scatter cursor to rowstart
__global__ __launch_bounds__(1024) void k_scan3(const int* __restrict__ bsum,
                                                int* __restrict__ row, int* __restrict__ cur){
    __shared__ int sadd;
    const int t = threadIdx.x;
    if (t < 64){
        int a = 0;
        for (int i = t; i < (int)blockIdx.x; i += 64) a += bsum[i];
        for (int off = 32; off; off >>= 1) a += __shfl_xor(a, off);
        if (t == 0) sadd = a;
    }
    __syncthreads();
    const int idx = blockIdx.x * 1024 + t;
    if (idx < NN){
        const int vfin = row[idx + 1] + sadd;
        row[idx + 1] = vfin;
        cur[idx + 1] = vfin;
    }
    if (idx == 0){ row[0] = 0; cur[0] = 0; }
}

// ---------------- kernel B: MFMA E-GEMM + alpha + v-pack + fused scatter + passthrough
// Barrier-free: wave w stages/E-GEMMs/packs exactly edges e0+w*16..+15.
__global__ __launch_bounds__(256) void k_edge4(
    const void* __restrict__ ea_raw, const int* __restrict__ flags,
    const bf16* __restrict__ WFe, const bf16* __restrict__ be,
    const bf16* __restrict__ kv_q, const bf16* __restrict__ kv_k, const bf16* __restrict__ kv_v,
    const int* __restrict__ srcI, const int* __restrict__ dstI, int* __restrict__ cur,
    unsigned short* __restrict__ alphap, unsigned short* __restrict__ vperm,
    void* __restrict__ outv)
{
    __shared__ unsigned short EA[64 * 64];    // 8 KB, ea tile bf16, swizzled
    __shared__ unsigned short ET[64 * 128];   // 16 KB, E tile bf16, swizzled
    const int t = threadIdx.x, lane = t & 63, wid = t >> 6;
    const int e0 = blockIdx.x * 64;
    const int row0 = wid * 16;

    // stage own 16 ea rows -> LDS (bf16) + fused raw passthrough write
    if (flags[0]){
        const float* ea = (const float*)ea_raw;
        float* outd = (float*)outv + (size_t)NN * CC;
        #pragma unroll
        for (int it = 0; it < 4; ++it){
            const int idx = lane + 64 * it;      // 256 units of 4 ch, own 16 rows
            const int row = row0 + (idx >> 4), c = (idx & 15) << 2;
            const size_t o = (size_t)(e0 + row) * EDIM + c;
            const float4 a = *(const float4*)&ea[o];
            *(float4*)&outd[o] = a;              // fused passthrough copy
            ushort4 b;
            b.x = f2u(a.x); b.y = f2u(a.y); b.z = f2u(a.z); b.w = f2u(a.w);
            *(ushort4*)((char*)EA + EASWZ(row, c >> 3) + ((c & 7) << 1)) = b;
        }
    } else {
        const unsigned short* ea = (const unsigned short*)ea_raw;
        unsigned short* outd = (unsigned short*)outv + (size_t)NN * CC;
        #pragma unroll
        for (int it = 0; it < 2; ++it){
            const int idx = lane + 64 * it;      // 128 units of 8 ch, own 16 rows
            const int row = row0 + (idx >> 3), c = (idx & 7) << 3;
            const size_t o = (size_t)(e0 + row) * EDIM + c;
            uint4 raw = *(const uint4*)&ea[o];
            *(uint4*)&outd[o] = raw;             // fused passthrough copy
            *(uint4*)((char*)EA + EASWZ(row, c >> 3)) = raw;
        }
    }
    // same-wave LDS ordering: no barrier needed

    // E-GEMM: wave wid computes edge-rows row0..row0+15 x 128 ch (K=64 -> 2 k-steps)
    {
        const int rA = row0 + (lane & 15);
        sh8 af[2];
        #pragma unroll
        for (int ks = 0; ks < 2; ++ks)
            af[ks] = *(const sh8*)((const char*)EA + EASWZ(rA, (ks << 2) + (lane >> 4)));
        f32x4 acc[8] = {};
        #pragma unroll
        for (int ks = 0; ks < 2; ++ks)
            #pragma unroll
            for (int ct = 0; ct < 8; ++ct){
                sh8 bfr = *(const sh8*)(WFe + ((size_t)((ct << 1) + ks) * 64 + lane) * 8);
                acc[ct] = __builtin_amdgcn_mfma_f32_16x16x32_bf16(af[ks], bfr, acc[ct], 0, 0, 0);
            }
        #pragma unroll
        for (int ct = 0; ct < 8; ++ct){
            const int c = (ct << 4) + (lane & 15);
            const float bv = b2f(be[c]);
            #pragma unroll
            for (int i = 0; i < 4; ++i){
                const int r = row0 + ((lane >> 4) << 2) + i;
                *(unsigned short*)((char*)ET + ASWZ(r, c >> 3) + ((c & 7) << 1)) =
                    f2u(acc[ct][i] + bv);
            }
        }
    }
    // same-wave LDS ordering: no barrier needed (pack reads own rows)

    // pack: thread handles 8 edges x 4 ch; fused atomic scatter + batched gathers (ILP)
    const int g = t >> 5, cT = t & 31, c = cT << 2;
    int s8[8], d8[8];
    #pragma unroll
    for (int i = 0; i < 8; ++i){
        const int eid = e0 + g * 8 + i;
        s8[i] = srcI[eid];
        d8[i] = dstI[eid];
    }
    // fused scatter: lanes cT<8 claim the CSR slot for edge cT of this group
    int pmine = 0;
    if (cT < 8) pmine = atomicAdd(&cur[dstI[e0 + g * 8 + cT]], 1);
    int p8[8];
    #pragma unroll
    for (int i = 0; i < 8; ++i)
        p8[i] = __shfl(pmine, ((g & 1) << 5) + i);

    ushort4 kr[8], vr[8], qr[8];
    #pragma unroll
    for (int i = 0; i < 8; ++i) kr[i] = *(const ushort4*)&kv_k[(size_t)s8[i] * CC + c];
    #pragma unroll
    for (int i = 0; i < 8; ++i) vr[i] = *(const ushort4*)&kv_v[(size_t)s8[i] * CC + c];
    #pragma unroll
    for (int i = 0; i < 8; ++i) qr[i] = *(const ushort4*)&kv_q[(size_t)d8[i] * CC + c];
    #pragma unroll
    for (int i = 0; i < 8; ++i){
        const ushort4 ev = *(const ushort4*)((const char*)ET + ASWZ(g * 8 + i, c >> 3) + ((c & 7) << 1));
        const float e0_ = u2f(ev.x), e1_ = u2f(ev.y), e2_ = u2f(ev.z), e3_ = u2f(ev.w);
        // alpha partial: q . (k + e) over this thread's 4 channels
        float part = u2f(qr[i].x) * (e0_ + u2f(kr[i].x)) + u2f(qr[i].y) * (e1_ + u2f(kr[i].y))
                   + u2f(qr[i].z) * (e2_ + u2f(kr[i].z)) + u2f(qr[i].w) * (e3_ + u2f(kr[i].w));
        part += __shfl_xor(part, 1);
        part += __shfl_xor(part, 2);           // full 16-ch head dot across 4 lanes
        if ((cT & 3) == 0)
            alphap[(size_t)p8[i] * 8 + (cT >> 2)] = f2u(part * 0.25f);   // 1/sqrt(16)
        ushort4 vo;
        vo.x = f2u(e0_ + u2f(vr[i].x)); vo.y = f2u(e1_ + u2f(vr[i].y));
        vo.z = f2u(e2_ + u2f(vr[i].z)); vo.w = f2u(e3_ + u2f(vr[i].w));
        *(ushort4*)&vperm[(size_t)p8[i] * CC + c] = vo;
    }
}

// ---------------- kernel C: streaming per-node softmax reduce (alpha precomputed) ----
__global__ __launch_bounds__(256) void k_attn3(
    const unsigned short* __restrict__ alphap, const bf16* __restrict__ vperm,
    const int* __restrict__ rowstart, bf16* __restrict__ attn_bf)
{
    const int t = threadIdx.x, lane = t & 63, wid = t >> 6;
    const int n = blockIdx.x * 4 + wid;
    const int h = lane >> 3;                   // head of this lane's 2 channels

    float m = -INFINITY, den = 0.0f;
    float2 num = make_float2(0.0f, 0.0f);

    const int jb = rowstart[n], je = rowstart[n + 1];
    for (int j = jb; j < je; ++j) {
        const float alpha = u2f(alphap[(size_t)j * 8 + h]);
        const float2 v2 = loadbf2(&vperm[(size_t)j * CC + 2 * lane]);
        if (alpha > m) {
            const float sc = __expf(m - alpha);
            den *= sc; num.x *= sc; num.y *= sc;
            m = alpha;
        }
        const float p = __expf(alpha - m);
        den += p;
        num.x += p * v2.x;
        num.y += p * v2.y;
    }
    const float inv = 1.0f / (den + 1e-16f);
    __hip_bfloat162 pr;
    pr.x = f2b(num.x * inv);
    pr.y = f2b(num.y * inv);
    *reinterpret_cast<__hip_bfloat162*>(&attn_bf[(size_t)n * CC + 2 * lane]) = pr;
}

// ---------------- kernel D: proj + residual + LN2 + MLP + residual (MFMA) ----------------
// Barrier-free: each wave stages and computes exactly its own 16 rows.
__global__ __launch_bounds__(256) void k_post2(
    const bf16* __restrict__ attn_bf, const bf16* __restrict__ xr,
    const void* __restrict__ x_raw,
    const bf16* __restrict__ WFp, const bf16* __restrict__ bp,
    const bf16* __restrict__ WF1, const bf16* __restrict__ b1,
    const bf16* __restrict__ WF2, const bf16* __restrict__ b2c,
    const bf16* __restrict__ g2, const bf16* __restrict__ bb2,
    void* __restrict__ outv, const int* __restrict__ flags)
{
    __shared__ unsigned short A[64 * 128];     // 16 KB
    __shared__ unsigned short HID[64 * 512];   // 64 KB
    const int t = threadIdx.x, lane = t & 63, wid = t >> 6;
    const int n0 = blockIdx.x * 64;
    const int f32io = flags[0];
    const int row0 = wid * 16;

    #pragma unroll
    for (int it = 0; it < 4; ++it){
        const int idx = lane + 64 * it;          // 256 chunks of 8 bf16, own 16 rows
        const int row = row0 + (idx >> 4), chunk = idx & 15, col = chunk << 3;
        unsigned w[4] = {0u, 0u, 0u, 0u};
        if (n0 + row < NN){
            const size_t o = (size_t)(n0 + row) * CC + col;
            uint4 a4 = *(const uint4*)&attn_bf[o];
            uint4 r4 = *(const uint4*)&xr[o];
            unsigned au[4] = {a4.x, a4.y, a4.z, a4.w};
            unsigned ru[4] = {r4.x, r4.y, r4.z, r4.w};
            #pragma unroll
            for (int j2 = 0; j2 < 4; ++j2){
                const float lo = u2f((unsigned short)(au[j2] & 0xFFFF)) +
                                 u2f((unsigned short)(ru[j2] & 0xFFFF));
                const float hi = u2f((unsigned short)(au[j2] >> 16)) +
                                 u2f((unsigned short)(ru[j2] >> 16));
                w[j2] = (unsigned)f2u(lo) | ((unsigned)f2u(hi) << 16);
            }
        }
        *(uint4*)((char*)A + ASWZ(row, chunk)) = make_uint4(w[0], w[1], w[2], w[3]);
    }
    // same-wave LDS ordering: no barrier needed

    const int rA = row0 + (lane & 15);

    float out2[8][4];
    {
        sh8 af[4];
        #pragma unroll
        for (int ks = 0; ks < 4; ++ks)
            af[ks] = *(const sh8*)((const char*)A + ASWZ(rA, (ks << 2) + (lane >> 4)));
        f32x4 acc[8] = {};
        #pragma unroll
        for (int ks = 0; ks < 4; ++ks)
            #pragma unroll
            for (int ct = 0; ct < 8; ++ct){
                sh8 bfr = *(const sh8*)(WFp + ((size_t)((ct << 2) + ks) * 64 + lane) * 8);
                acc[ct] = __builtin_amdgcn_mfma_f32_16x16x32_bf16(af[ks], bfr, acc[ct], 0, 0, 0);
            }
        #pragma unroll
        for (int ct = 0; ct < 8; ++ct){
            const int c = (ct << 4) + (lane & 15);
            const float bv = b2f(bp[c]);
            #pragma unroll
            for (int i = 0; i < 4; ++i){
                const int r = row0 + ((lane >> 4) << 2) + i;
                float xs = 0.f;
                if (n0 + r < NN){
                    const size_t o = (size_t)(n0 + r) * CC + c;
                    xs = f32io ? ((const float*)x_raw)[o] : b2f(((const bf16*)x_raw)[o]);
                }
                out2[ct][i] = acc[ct][i] + bv + xs;
            }
        }
    }

    { // LN2 in registers, write normalized bf16 -> A (same-wave rows only)
        float mu[4], rstd[4];
        #pragma unroll
        for (int i = 0; i < 4; ++i){
            float s = 0.f;
            #pragma unroll
            for (int ct = 0; ct < 8; ++ct) s += out2[ct][i];
            s += __shfl_xor(s, 1); s += __shfl_xor(s, 2);
            s += __shfl_xor(s, 4); s += __shfl_xor(s, 8);
            mu[i] = s * (1.0f / CC);
        }
        #pragma unroll
        for (int i = 0; i < 4; ++i){
            float vv = 0.f;
            #pragma unroll
            for (int ct = 0; ct < 8; ++ct){ const float d = out2[ct][i] - mu[i]; vv += d * d; }
            vv += __shfl_xor(vv, 1); vv += __shfl_xor(vv, 2);
            vv += __shfl_xor(vv, 4); vv += __shfl_xor(vv, 8);
            rstd[i] = rsqrtf(vv * (1.0f / CC) + 1e-5f);
        }
        #pragma unroll
        for (int ct = 0; ct < 8; ++ct){
            const int c = (ct << 4) + (lane & 15);
            const float gv = b2f(g2[c]), bbv = b2f(bb2[c]);
            const int chunk = c >> 3;
            #pragma unroll
            for (int i = 0; i < 4; ++i){
                const int r = row0 + ((lane >> 4) << 2) + i;
                const float ln = (out2[ct][i] - mu[i]) * rstd[i] * gv + bbv;
                *(unsigned short*)((char*)A + ASWZ(r, chunk) + ((c & 7) << 1)) = f2u(ln);
            }
        }
    }

    { // GEMM2: hid = gelu(LN2 @ w1 + b1) -> HID
        sh8 af[4];
        #pragma unroll
        for (int ks = 0; ks < 4; ++ks)
            af[ks] = *(const sh8*)((const char*)A + ASWZ(rA, (ks << 2) + (lane >> 4)));
        #pragma unroll
        for (int grp = 0; grp < 4; ++grp){
            f32x4 acc[8] = {};
            #pragma unroll
            for (int ks = 0; ks < 4; ++ks)
                #pragma unroll
                for (int ctl = 0; ctl < 8; ++ctl){
                    const int ct = grp * 8 + ctl;
                    sh8 bfr = *(const sh8*)(WF1 + ((size_t)((ct << 2) + ks) * 64 + lane) * 8);
                    acc[ctl] = __builtin_amdgcn_mfma_f32_16x16x32_bf16(af[ks], bfr, acc[ctl], 0, 0, 0);
                }
            #pragma unroll
            for (int ctl = 0; ctl < 8; ++ctl){
                const int ct = grp * 8 + ctl;
                const int c = (ct << 4) + (lane & 15);
                const float bv = b2f(b1[c]);
                const int chunk = c >> 3;
                #pragma unroll
                for (int i = 0; i < 4; ++i){
                    const int r = row0 + ((lane >> 4) << 2) + i;
                    const float h = gelu_tanh(acc[ctl][i] + bv);
                    *(unsigned short*)((char*)HID + HSWZ(r, chunk) + ((c & 7) << 1)) = f2u(h);
                }
            }
        }
    }

    { // GEMM3: o = hid @ w2 ; final = out2 + o + b2
        f32x4 acc[8] = {};
        #pragma unroll
        for (int ks = 0; ks < 16; ++ks){
            sh8 afh = *(const sh8*)((const char*)HID + HSWZ(rA, (ks << 2) + (lane >> 4)));
            #pragma unroll
            for (int ct = 0; ct < 8; ++ct){
                sh8 bfr = *(const sh8*)(WF2 + ((size_t)((ct << 4) + ks) * 64 + lane) * 8);
                acc[ct] = __builtin_amdgcn_mfma_f32_16x16x32_bf16(afh, bfr, acc[ct], 0, 0, 0);
            }
        }
        #pragma unroll
        for (int ct = 0; ct < 8; ++ct){
            const int c = (ct << 4) + (lane & 15);
            const float bv = b2f(b2c[c]);
            #pragma unroll
            for (int i = 0; i < 4; ++i){
                const int r = row0 + ((lane >> 4) << 2) + i;
                if (n0 + r < NN){
                    const float val = out2[ct][i] + acc[ct][i] + bv;
                    if (f32io) ((float*)outv)[(size_t)(n0 + r) * CC + c] = val;
                    else       ((bf16*)outv)[(size_t)(n0 + r) * CC + c] = f2b(val);
                }
            }
        }
    }
}

extern "C" void kernel_launch(void* const* d_in, const int* in_sizes, int n_in,
                              void* d_out, int out_size, void* d_ws, size_t ws_size,
                              hipStream_t stream)
{
    if (ws_size < WS_NEED) {
        fprintf(stderr, "[kl] WS TOO SMALL ws=%zu need=%zu\n", ws_size, WS_NEED);
        return;
    }

    char* ws = (char*)d_ws;
    int*  flags = (int*)(ws + OFF_FLAG);
    int*  deg   = (int*)(ws + OFF_DEG);
    int*  row   = (int*)(ws + OFF_ROW);
    int*  cur   = (int*)(ws + OFF_CUR);
    int*  srcI  = (int*)(ws + OFF_SRC);
    int*  dstI  = (int*)(ws + OFF_DST);
    int*  bsum  = (int*)(ws + OFF_BSUM);
    bf16* qC    = (bf16*)(ws + OFF_QC);
    bf16* kC    = (bf16*)(ws + OFF_KC);
    bf16* vC    = (bf16*)(ws + OFF_VC);
    bf16* attC  = (bf16*)(ws + OFF_ATT);
    bf16* xrC   = (bf16*)(ws + OFF_XRC);
    unsigned short* alphap = (unsigned short*)(ws + OFF_ALP);
    unsigned short* vperm  = (unsigned short*)(ws + OFF_VP);
    bf16* WFq = (bf16*)(ws + OFF_WFQ);
    bf16* WFk = (bf16*)(ws + OFF_WFK);
    bf16* WFv = (bf16*)(ws + OFF_WFV);
    bf16* WFs = (bf16*)(ws + OFF_WFS);
    bf16* WFp = (bf16*)(ws + OFF_WFP);
    bf16* WF1 = (bf16*)(ws + OFF_WF1);
    bf16* WF2 = (bf16*)(ws + OFF_WF2);
    bf16* WFe = (bf16*)(ws + OFF_WFE);

    bf16* P = (bf16*)(ws + OFF_PRM);
    bf16 *bqC=P; P+=128; bf16 *bkC=P; P+=128;
    bf16 *bvC=P; P+=128; bf16 *bsC=P; P+=128;
    bf16 *beC=P; P+=128; bf16 *bpC=P; P+=128;
    bf16 *b1C=P; P+=512; bf16 *b2C=P; P+=128;
    bf16 *g1C=P; P+=128; bf16 *n1C=P; P+=128;
    bf16 *g2C=P; P+=128; bf16 *n2C=P; P+=128;

    hipMemsetAsync(deg, 0, (size_t)(NN + 1) * sizeof(int), stream);

    // 1) detect dtypes
    k_detect<<<1, 256, 0, stream>>>((const unsigned short*)d_in[0],
                                    (const unsigned int*)d_in[2], flags);

    // 2) canonicalize biases/LN (tiny) + indices (+deg histogram fused)
    {
        CvtJobs cj;
        bf16* dsts[12] = {bqC,bkC,bvC,bsC,beC,bpC,b1C,b2C,g1C,n1C,g2C,n2C};
        const int idxs[12] = {4,6,8,10,12,14,16,18,19,20,21,22};
        const int ns[12]   = {128,128,128,128,128,128,512,128,128,128,128,128};
        for (int i = 0; i < 12; ++i){ cj.j[i].s = d_in[idxs[i]]; cj.j[i].d = dsts[i]; cj.j[i].n = ns[i]; }
        k_cvt_all<<<12 * 2, 256, 0, stream>>>(cj, flags);
    }
    k_cvt_idx<<<1024, 256, 0, stream>>>((const int*)d_in[2], srcI, dstI, deg, flags);

    // 3) weight fragment pre-transform straight from RAW inputs (one launch, 8 jobs)
    {
        WJobs wj;
        const WJob js[8] = {{d_in[3],WFq,128,128},{d_in[5],WFk,128,128},{d_in[7],WFv,128,128},
                            {d_in[9],WFs,128,128},{d_in[13],WFp,128,128},{d_in[15],WF1,128,512},
                            {d_in[17],WF2,512,128},{d_in[11],WFe,64,128}};
        for (int i = 0; i < 8; ++i) wj.j[i] = js[i];
        k_wprep_all<<<8 * 48, 256, 0, stream>>>(wj, flags);
    }

    // 4) pipeline
    const int NB64 = (NN + 63) / 64;
    const int NSC  = (NN + 1023) / 1024;
    k_node_pre2<<<NB64, 256, 0, stream>>>(d_in[0], flags, WFq, bqC, WFk, bkC, WFv, bvC,
                                          WFs, bsC, g1C, n1C, qC, kC, vC, xrC);
    k_scan1<<<NSC, 1024, 0, stream>>>(deg, row, bsum);
    k_scan3<<<NSC, 1024, 0, stream>>>(bsum, row, cur);
    k_edge4<<<NE / 64, 256, 0, stream>>>(d_in[1], flags, WFe, beC, qC, kC, vC,
                                         srcI, dstI, cur, alphap, vperm, d_out);
    k_attn3<<<NN / 4, 256, 0, stream>>>(alphap, (const bf16*)vperm, row, attC);
    k_post2<<<NB64, 256, 0, stream>>>(attC, xrC, d_in[0], WFp, bpC, WF1, b1C, WF2, b2C,
                                      g2C, n2C, d_out, flags);
}